// Round 9
// baseline (298.613 us; speedup 1.0000x reference)
//
#include <hip/hip_runtime.h>
#include <stdint.h>
#include <stddef.h>

#define M_DIM 2048
#define N_DIM 11008
#define K_DIM 4096
#define BM 128
#define BN 128
#define BK 32
#define NT (K_DIM / BK)   // 128
#define NBM (M_DIM / BM)  // 16
#define NBN (N_DIM / BN)  // 86
#define GRID (NBM * NBN)  // 1376 (divisible by 8 -> XCD swizzle bijective)

typedef __attribute__((ext_vector_type(4))) float f32x4;
typedef __attribute__((ext_vector_type(4))) float f4;
typedef __attribute__((ext_vector_type(4))) int i4;
typedef __attribute__((ext_vector_type(8))) __bf16 bf16x8;
typedef __attribute__((ext_vector_type(8))) unsigned short us8;

#define VMCNT4() asm volatile("s_waitcnt vmcnt(4)" ::: "memory")
#define VMCNT0() asm volatile("s_waitcnt vmcnt(0)" ::: "memory")
#define FENCE() asm volatile("" ::: "memory")
#define BARRIER()                 \
  do {                            \
    FENCE();                      \
    __builtin_amdgcn_s_barrier(); \
    FENCE();                      \
  } while (0)

// round-to-nearest-even fp32 -> bf16
__device__ inline unsigned short f2bf(float f) {
  unsigned u = __builtin_bit_cast(unsigned, f);
  u += 0x7fffu + ((u >> 16) & 1u);
  return (unsigned short)(u >> 16);
}

__device__ inline void gload_lds16(const void* g, void* l) {
  __builtin_amdgcn_global_load_lds((const __attribute__((address_space(1))) void*)g,
                                   (__attribute__((address_space(3))) void*)l, 16, 0, 0);
}

// ---------------- conversion kernels ----------------

__global__ void __launch_bounds__(256) cvt_x_kernel(const float* __restrict__ x,
                                                    us8* __restrict__ xb, int n8) {
  int i = blockIdx.x * 256 + threadIdx.x;
  if (i >= n8) return;
  const f4* src = (const f4*)x;
  f4 a = src[2 * i];
  f4 b = src[2 * i + 1];
  us8 o;
  o[0] = f2bf(a[0]); o[1] = f2bf(a[1]); o[2] = f2bf(a[2]); o[3] = f2bf(a[3]);
  o[4] = f2bf(b[0]); o[5] = f2bf(b[1]); o[6] = f2bf(b[2]); o[7] = f2bf(b[3]);
  xb[i] = o;
}

// W_q arrives as int32 per element; int8-range values are exact in bf16.
__global__ void __launch_bounds__(256) cvt_w_kernel(const int* __restrict__ w,
                                                    us8* __restrict__ wb, int n16) {
  int i = blockIdx.x * 256 + threadIdx.x;
  if (i >= n16) return;
  const i4* src = (const i4*)w + 4 * (size_t)i;
  i4 v0 = src[0], v1 = src[1], v2 = src[2], v3 = src[3];
  us8 lo, hi;
  lo[0] = f2bf((float)v0[0]); lo[1] = f2bf((float)v0[1]);
  lo[2] = f2bf((float)v0[2]); lo[3] = f2bf((float)v0[3]);
  lo[4] = f2bf((float)v1[0]); lo[5] = f2bf((float)v1[1]);
  lo[6] = f2bf((float)v1[2]); lo[7] = f2bf((float)v1[3]);
  hi[0] = f2bf((float)v2[0]); hi[1] = f2bf((float)v2[1]);
  hi[2] = f2bf((float)v2[2]); hi[3] = f2bf((float)v2[3]);
  hi[4] = f2bf((float)v3[0]); hi[5] = f2bf((float)v3[1]);
  hi[6] = f2bf((float)v3[2]); hi[7] = f2bf((float)v3[3]);
  wb[2 * (size_t)i] = lo;
  wb[2 * (size_t)i + 1] = hi;
}

// ------- 3-blocks/CU GEMM: 128x128 tile, BK=32, 4 waves, 48KB triple-buffer LDS -------
// 4 waves = 2M x 2N, wave-tile 64x64 over K=32: 8 ds_read_b128 + 16 MFMA per tile.
// LDS: 3 bufs x 16KB {A[128][32]@0, B[128][32]@8K}. NT=128 K-tiles.
// Iter t: vmcnt(4) [retires S(t), issued at t-2 -> ~2 block-iters slack]; barrier
//   [publish S(t); readers of buf (t-1)%3 drained: their lgkm waits precede MFMAs(t-1),
//   which precede barrier(t)]; STAGE4(t+2) -> buf (t+2)%3; reads; 16 MFMA.
// vmcnt ledger: top of t outstanding = S(t) 4 + S(t+1) 4 = 8 -> vmcnt(4) retires S(t).
// Tail: t=NT-1 -> vmcnt(0). One barrier + one counted wait per K-tile.
// TLP: 3 blocks/CU (LDS 144KB, regs ~128) = 12 waves, 3 independent barrier domains.
// NOTE: buffers rotate via three named pointers (bc/bnx/bnn) — an indexed array of
// LDS pointers fails gfx950 codegen (addrspacecast static init) and would hit scratch.

#define STAGE4(base, ko)                                                         \
  do {                                                                           \
    const int _ko = (ko);                                                        \
    gload_lds16(gA + _ko, (base) + wid * 1024);                                  \
    gload_lds16(gA + (size_t)64 * K_DIM + _ko, (base) + 4096 + wid * 1024);      \
    gload_lds16(gB + _ko, (base) + 8192 + wid * 1024);                           \
    gload_lds16(gB + (size_t)64 * K_DIM + _ko, (base) + 12288 + wid * 1024);     \
  } while (0)

__global__ void __launch_bounds__(256, 3) gemm_pipe(
    const unsigned short* __restrict__ Xb,   // [M, K] bf16
    const unsigned short* __restrict__ Wb,   // [N, K] bf16
    const float* __restrict__ scale,         // [N]
    const float* __restrict__ bias,          // [N]
    float* __restrict__ out) {               // [M, N] fp32
  __shared__ __align__(16) char lds[49152];  // 3 x 16KB

  const int tid = threadIdx.x;
  const int lane = tid & 63;
  const int wid = tid >> 6;   // 0..3
  const int wm = wid >> 1;    // M-half (64 rows)
  const int wn = wid & 1;     // N-half (64 cols)
  const int fr = lane & 15;
  const int fq = lane >> 4;

  // T1: XCD-aware swizzle (1376 % 8 == 0 -> bijective). Consecutive wg share bn.
  const int bid = blockIdx.x;
  const int wg = (bid & 7) * (GRID / 8) + (bid >> 3);
  const int bm = wg & 15;
  const int bn = wg >> 4;

  // staging source (inverse-swizzled): row = tid>>2 (+64 for 2nd chunk),
  // granule = (tid&3) ^ (row&3); 64B rows, 4 x 16B granules per row.
  const int srow = tid >> 2;
  const int scol = ((tid & 3) ^ (srow & 3)) * 8;  // elements
  const unsigned short* gA = Xb + (size_t)(bm * BM + srow) * K_DIM + scol;
  const unsigned short* gB = Wb + (size_t)(bn * BN + srow) * K_DIM + scol;

  // ds_read: byte = row*64 + ((fq*16) ^ ((row&3)<<4)); row&3 == fr&3 == lane&3
  const int cb = (fq << 4) ^ ((lane & 3) << 4);
  const int arow = (wm * 64 + fr) * 64;         // + m*1024
  const int brow = 8192 + (wn * 64 + fr) * 64;  // + j*1024

  // ---- prologue: stage tiles 0,1 (depth-2 prefetch from the start)
  char* bc = lds;            // buf for tile t
  char* bnx = lds + 16384;   // buf for tile t+1
  char* bnn = lds + 32768;   // buf for tile t+2 (staging target)
  STAGE4(bc, 0);
  STAGE4(bnx, BK);

  f32x4 acc[4][4] = {};

#pragma unroll 1
  for (int t = 0; t < NT; ++t) {
    if (t < NT - 1) { VMCNT4(); } else { VMCNT0(); }
    BARRIER();   // publish S(t); all reads of buf (t-1)%3 == bnn already drained
    if (t + 2 < NT) STAGE4(bnn, (t + 2) * BK);

    bf16x8 a[4], b[4];
#pragma unroll
    for (int m = 0; m < 4; ++m)
      a[m] = *(const bf16x8*)(bc + arow + m * 1024 + cb);
#pragma unroll
    for (int j = 0; j < 4; ++j)
      b[j] = *(const bf16x8*)(bc + brow + j * 1024 + cb);
    __builtin_amdgcn_s_setprio(1);
#pragma unroll
    for (int m = 0; m < 4; ++m)
#pragma unroll
      for (int j = 0; j < 4; ++j)
        acc[m][j] = __builtin_amdgcn_mfma_f32_16x16x32_bf16(a[m], b[j], acc[m][j], 0, 0, 0);
    __builtin_amdgcn_s_setprio(0);

    char* tmp = bc; bc = bnx; bnx = bnn; bnn = tmp;
  }

  // ---- epilogue: direct store with scale/bias (fp32)
  // C/D frag layout: col = j*16+fr, row = m*16 + fq*4 + jj (within wave's 64x64 tile)
#pragma unroll
  for (int j = 0; j < 4; ++j) {
    const int c = bn * BN + wn * 64 + j * 16 + fr;
    const float sc = scale[c];
    const float bi = bias[c];
#pragma unroll
    for (int m = 0; m < 4; ++m) {
      const int r0 = bm * BM + wm * 64 + m * 16 + fq * 4;
#pragma unroll
      for (int jj = 0; jj < 4; ++jj)
        out[(size_t)(r0 + jj) * N_DIM + c] = acc[m][j][jj] * sc + bi;
    }
  }
}

// ---------------- fallback (only if d_ws too small) ----------------

__global__ void __launch_bounds__(256) naive_kernel(
    const float* __restrict__ x, const int* __restrict__ w,
    const float* __restrict__ scale, const float* __restrict__ bias,
    float* __restrict__ out) {
  size_t idx = (size_t)blockIdx.x * 256 + threadIdx.x;
  if (idx >= (size_t)M_DIM * N_DIM) return;
  int m = (int)(idx / N_DIM);
  int n = (int)(idx % N_DIM);
  const float* xr = x + (size_t)m * K_DIM;
  const int* wr = w + (size_t)n * K_DIM;
  float acc = 0.f;
  for (int k = 0; k < K_DIM; k += 4) {
    f4 xv = *(const f4*)(xr + k);
    i4 wv = *(const i4*)(wr + k);
    acc += xv[0] * (float)wv[0];
    acc += xv[1] * (float)wv[1];
    acc += xv[2] * (float)wv[2];
    acc += xv[3] * (float)wv[3];
  }
  out[idx] = acc * scale[n] + bias[n];
}

// ---------------- launch ----------------

extern "C" void kernel_launch(void* const* d_in, const int* in_sizes, int n_in,
                              void* d_out, int out_size, void* d_ws, size_t ws_size,
                              hipStream_t stream) {
  const float* x = (const float*)d_in[0];
  const int* wq = (const int*)d_in[1];
  const float* scale = (const float*)d_in[2];
  const float* bias = (const float*)d_in[3];
  float* out = (float*)d_out;

  const size_t xb_bytes = (size_t)M_DIM * K_DIM * 2;   // 16.8 MB
  const size_t wb_bytes = (size_t)N_DIM * K_DIM * 2;   // 90.2 MB

  if (ws_size >= xb_bytes + wb_bytes) {
    unsigned short* xb = (unsigned short*)d_ws;
    unsigned short* wb = (unsigned short*)((char*)d_ws + xb_bytes);

    const int n8 = M_DIM * K_DIM / 8;
    cvt_x_kernel<<<(n8 + 255) / 256, 256, 0, stream>>>(x, (us8*)xb, n8);

    const int n16 = N_DIM * K_DIM / 16;
    cvt_w_kernel<<<(n16 + 255) / 256, 256, 0, stream>>>(wq, (us8*)wb, n16);

    gemm_pipe<<<GRID, 256, 0, stream>>>(xb, wb, scale, bias, out);
  } else {
    const size_t total = (size_t)M_DIM * N_DIM;
    naive_kernel<<<(unsigned)((total + 255) / 256), 256, 0, stream>>>(x, wq, scale, bias, out);
  }
}

// Round 10
// 162.036 us; speedup vs baseline: 1.8429x; 1.8429x over previous
//
#include <hip/hip_runtime.h>
#include <stdint.h>
#include <stddef.h>

#define M_DIM 2048
#define N_DIM 11008
#define K_DIM 4096
#define BM 128
#define BN 128
#define BKB 128            // K-bytes per tile (int8) -> 128B rows, same geometry as r7
#define NT (K_DIM / BKB)   // 32
#define NBM (M_DIM / BM)   // 16
#define NBN (N_DIM / BN)   // 86
#define GRID (NBM * NBN)   // 1376 (divisible by 8 -> XCD swizzle bijective)

typedef __attribute__((ext_vector_type(4))) int i4;
typedef __attribute__((ext_vector_type(4))) float f4;
typedef __attribute__((ext_vector_type(8))) unsigned short us8;

#define VMCNT0() asm volatile("s_waitcnt vmcnt(0)" ::: "memory")
#define FENCE() asm volatile("" ::: "memory")
#define BARRIER()                 \
  do {                            \
    FENCE();                      \
    __builtin_amdgcn_s_barrier(); \
    FENCE();                      \
  } while (0)

__device__ inline void gload_lds16(const void* g, void* l) {
  __builtin_amdgcn_global_load_lds((const __attribute__((address_space(1))) void*)g,
                                   (__attribute__((address_space(3))) void*)l, 16, 0, 0);
}

// ---------------- conversion kernels ----------------

// x[row][4096] fp32 -> per-row int8 with scale xs[row] = rowmax/127 (symmetric RNE).
__global__ void __launch_bounds__(256) quant_x_kernel(const float* __restrict__ x,
                                                      signed char* __restrict__ xq,
                                                      float* __restrict__ xs) {
  __shared__ float red[256];
  const int row = blockIdx.x;
  const int tid = threadIdx.x;
  const f4* xr = (const f4*)(x + (size_t)row * K_DIM);  // 1024 f4 per row
  f4 v[4];
  float mx = 0.f;
#pragma unroll
  for (int j = 0; j < 4; ++j) {
    v[j] = xr[tid * 4 + j];
#pragma unroll
    for (int e = 0; e < 4; ++e) mx = fmaxf(mx, fabsf(v[j][e]));
  }
  red[tid] = mx;
  __syncthreads();
  for (int off = 128; off; off >>= 1) {
    if (tid < off) red[tid] = fmaxf(red[tid], red[tid + off]);
    __syncthreads();
  }
  const float rowmax = red[0];
  const float r = (rowmax > 0.f) ? 127.f / rowmax : 0.f;
  int p[4];
#pragma unroll
  for (int j = 0; j < 4; ++j) {
    int q[4];
#pragma unroll
    for (int e = 0; e < 4; ++e) {
      int qi = __float2int_rn(v[j][e] * r);
      qi = qi > 127 ? 127 : (qi < -127 ? -127 : qi);
      q[e] = qi;
    }
    p[j] = (q[0] & 255) | ((q[1] & 255) << 8) | ((q[2] & 255) << 16) | (q[3] << 24);
  }
  ((i4*)xq)[(size_t)row * 256 + tid] = i4{p[0], p[1], p[2], p[3]};
  if (tid == 0) xs[row] = (rowmax > 0.f) ? rowmax / 127.f : 1.f;
}

// W_q arrives as int32 per element (range [-127,127]); pack low bytes -> int8.
__global__ void __launch_bounds__(256) cvt_w_kernel(const int* __restrict__ w,
                                                    i4* __restrict__ wq8, int n16) {
  int i = blockIdx.x * 256 + threadIdx.x;
  if (i >= n16) return;
  const i4* src = (const i4*)w + 4 * (size_t)i;
  i4 v0 = src[0], v1 = src[1], v2 = src[2], v3 = src[3];
  i4 o;
  o[0] = (v0[0] & 255) | ((v0[1] & 255) << 8) | ((v0[2] & 255) << 16) | (v0[3] << 24);
  o[1] = (v1[0] & 255) | ((v1[1] & 255) << 8) | ((v1[2] & 255) << 16) | (v1[3] << 24);
  o[2] = (v2[0] & 255) | ((v2[1] & 255) << 8) | ((v2[2] & 255) << 16) | (v2[3] << 24);
  o[3] = (v3[0] & 255) | ((v3[1] & 255) << 8) | ((v3[2] & 255) << 16) | (v3[3] << 24);
  wq8[i] = o;
}

// ------- int8 GEMM, r7-winning schedule: 128x128 tile, BKB=128, 4 waves, 64KB LDS -------
// 4 waves = 2 N-strips (64 cols) x 2 K-halves (64 of 128 bytes); wave-tile 128x64.
// Per wave per tile: 12 ds_read_b128 (a 8, b 4) + 32 x mfma_i32_16x16x64_i8.
// LDS: 2 bufs x 32KB {A[128][128B]@0, B[128][128B]@16K}; identical byte-geometry to r7
// (128B rows, XOR swizzle byte^=(row&7)<<4 both sides -> 0 bank conflicts, measured r3-r7).
// Iter t: vmcnt(0) [== counted: only S(t)'s 8 loads outstanding, issued iter t-1];
// barrier; STAGE8(t+1) -> other buf; reads; 2 MFMA clusters under setprio.
// Epilogue: K-half i32 reduce via LDS (fq-XOR, 2-way=free), then
// out = (float)acc * xs[row] * scale[col] + bias[col]. int32 accumulation exact.

#define STAGE8(base, gA, gB, ko)                                                 \
  do {                                                                           \
    const int _ko = (ko);                                                        \
    gload_lds16((gA) + _ko, (base) + wid * 1024);                                \
    gload_lds16((gA) + (size_t)32 * K_DIM + _ko, (base) + 4096 + wid * 1024);    \
    gload_lds16((gA) + (size_t)64 * K_DIM + _ko, (base) + 8192 + wid * 1024);    \
    gload_lds16((gA) + (size_t)96 * K_DIM + _ko, (base) + 12288 + wid * 1024);   \
    gload_lds16((gB) + _ko, (base) + 16384 + wid * 1024);                        \
    gload_lds16((gB) + (size_t)32 * K_DIM + _ko, (base) + 20480 + wid * 1024);   \
    gload_lds16((gB) + (size_t)64 * K_DIM + _ko, (base) + 24576 + wid * 1024);   \
    gload_lds16((gB) + (size_t)96 * K_DIM + _ko, (base) + 28672 + wid * 1024);   \
  } while (0)

__global__ void __launch_bounds__(256, 2) gemm_i8(
    const signed char* __restrict__ Xq,   // [M, K] int8
    const signed char* __restrict__ Wq,   // [N, K] int8
    const float* __restrict__ xs,         // [M] row scales
    const float* __restrict__ scale,      // [N]
    const float* __restrict__ bias,       // [N]
    float* __restrict__ out) {            // [M, N] fp32
  __shared__ __align__(16) char lds[65536];  // 2 x 32KB; epilogue reuses 64KB

  const int tid = threadIdx.x;
  const int lane = tid & 63;
  const int wid = tid >> 6;   // 0..3
  const int s = wid & 1;      // N-strip (64 cols)
  const int h = wid >> 1;     // K-half (64 bytes of 128)
  const int fr = lane & 15;
  const int fq = lane >> 4;

  // T1: XCD-aware swizzle (1376 % 8 == 0 -> bijective). Consecutive wg share bn.
  const int bid = blockIdx.x;
  const int wg = (bid & 7) * (GRID / 8) + (bid >> 3);
  const int bm = wg & 15;
  const int bn = wg >> 4;

  // staging source (inverse-swizzled): row = tid>>3 (+32*i), granule = (tid&7)^(row&7)
  const int srow = tid >> 3;
  const int scol = ((tid & 7) ^ (srow & 7)) * 16;  // bytes
  const signed char* gA = Xq + (size_t)(bm * BM + srow) * K_DIM + scol;
  const signed char* gB = Wq + (size_t)(bn * BN + srow) * K_DIM + scol;

  // ds_read: byte col = (h*64 + fq*16) ^ ((row&7)<<4); row&7 == lane&7 for all frags
  const int cb = ((h * 64) + (fq * 16)) ^ ((lane & 7) << 4);

  char* const buf0 = lds;
  char* const buf1 = lds + 32768;

  STAGE8(buf0, gA, gB, 0);

  i4 acc[8][4] = {};

#pragma unroll 1
  for (int t = 0; t < NT; ++t) {
    char* const bc = (t & 1) ? buf1 : buf0;
    char* const bo = (t & 1) ? buf0 : buf1;
    VMCNT0();    // S(t) complete (issued iter t-1; ~1 iter slack)
    BARRIER();   // publish bc; prior readers of bo drained pre-barrier
    if (t + 1 < NT) STAGE8(bo, gA, gB, (t + 1) * BKB);

    i4 a[8], b[4];
#pragma unroll
    for (int m = 0; m < 8; ++m)
      a[m] = *(const i4*)(bc + (m * 16 + fr) * 128 + cb);
#pragma unroll
    for (int j = 0; j < 4; ++j)
      b[j] = *(const i4*)(bc + 16384 + (s * 64 + j * 16 + fr) * 128 + cb);
    __builtin_amdgcn_s_setprio(1);
#pragma unroll
    for (int m = 0; m < 4; ++m)
#pragma unroll
      for (int j = 0; j < 4; ++j)
        acc[m][j] = __builtin_amdgcn_mfma_i32_16x16x64_i8(a[m], b[j], acc[m][j], 0, 0, 0);
    __builtin_amdgcn_s_setprio(0);
    __builtin_amdgcn_s_setprio(1);
#pragma unroll
    for (int m = 4; m < 8; ++m)
#pragma unroll
      for (int j = 0; j < 4; ++j)
        acc[m][j] = __builtin_amdgcn_mfma_i32_16x16x64_i8(a[m], b[j], acc[m][j], 0, 0, 0);
    __builtin_amdgcn_s_setprio(0);
  }

  // ---- epilogue: reduce K-half pairs via LDS (i32, fq-XOR swizzle -> 2-way, free),
  // then dequant + bias + store. C/D frag: col=j*16+fr, row=m*16+fq*4+jj.
  BARRIER();
  if (h == 1) {
    int* red = (int*)(lds + s * 32768);  // [128][64] i32 per strip
#pragma unroll
    for (int m = 0; m < 8; ++m)
#pragma unroll
      for (int j = 0; j < 4; ++j)
#pragma unroll
        for (int jj = 0; jj < 4; ++jj)
          red[(m * 16 + fq * 4 + jj) * 64 + ((j * 16 + fr) ^ (fq << 4))] = acc[m][j][jj];
  }
  BARRIER();
  if (h == 0) {
    const int* red = (const int*)(lds + s * 32768);
#pragma unroll
    for (int j = 0; j < 4; ++j) {
      const int c = bn * BN + s * 64 + j * 16 + fr;
      const float sc = scale[c];
      const float bi = bias[c];
#pragma unroll
      for (int m = 0; m < 8; ++m) {
        const int r0 = bm * BM + m * 16 + fq * 4;
#pragma unroll
        for (int jj = 0; jj < 4; ++jj) {
          const int sum = acc[m][j][jj] +
                          red[(m * 16 + fq * 4 + jj) * 64 + ((j * 16 + fr) ^ (fq << 4))];
          out[(size_t)(r0 + jj) * N_DIM + c] = (float)sum * xs[r0 + jj] * sc + bi;
        }
      }
    }
  }
}

// ---------------- fallback (only if d_ws too small) ----------------

__global__ void __launch_bounds__(256) naive_kernel(
    const float* __restrict__ x, const int* __restrict__ w,
    const float* __restrict__ scale, const float* __restrict__ bias,
    float* __restrict__ out) {
  size_t idx = (size_t)blockIdx.x * 256 + threadIdx.x;
  if (idx >= (size_t)M_DIM * N_DIM) return;
  int m = (int)(idx / N_DIM);
  int n = (int)(idx % N_DIM);
  const float* xr = x + (size_t)m * K_DIM;
  const int* wr = w + (size_t)n * K_DIM;
  float acc = 0.f;
  for (int k = 0; k < K_DIM; k += 4) {
    f4 xv = *(const f4*)(xr + k);
    i4 wv = *(const i4*)(wr + k);
    acc += xv[0] * (float)wv[0];
    acc += xv[1] * (float)wv[1];
    acc += xv[2] * (float)wv[2];
    acc += xv[3] * (float)wv[3];
  }
  out[idx] = acc * scale[n] + bias[n];
}

// ---------------- launch ----------------

extern "C" void kernel_launch(void* const* d_in, const int* in_sizes, int n_in,
                              void* d_out, int out_size, void* d_ws, size_t ws_size,
                              hipStream_t stream) {
  const float* x = (const float*)d_in[0];
  const int* wq = (const int*)d_in[1];
  const float* scale = (const float*)d_in[2];
  const float* bias = (const float*)d_in[3];
  float* out = (float*)d_out;

  const size_t xq_bytes = (size_t)M_DIM * K_DIM;        // 8.4 MB
  const size_t xs_bytes = (size_t)M_DIM * sizeof(float); // 8 KB
  const size_t wq_bytes = (size_t)N_DIM * K_DIM;        // 45.1 MB

  if (ws_size >= xq_bytes + xs_bytes + wq_bytes) {
    signed char* xq = (signed char*)d_ws;
    float* xs = (float*)((char*)d_ws + xq_bytes);
    signed char* wq8 = (signed char*)((char*)d_ws + xq_bytes + xs_bytes);

    quant_x_kernel<<<M_DIM, 256, 0, stream>>>(x, xq, xs);

    const int n16 = N_DIM * K_DIM / 16;
    cvt_w_kernel<<<(n16 + 255) / 256, 256, 0, stream>>>(wq, (i4*)wq8, n16);

    gemm_i8<<<GRID, 256, 0, stream>>>(xq, wq8, xs, scale, bias, out);
  } else {
    const size_t total = (size_t)M_DIM * N_DIM;
    naive_kernel<<<(unsigned)((total + 255) / 256), 256, 0, stream>>>(x, wq, scale, bias, out);
  }
}